// Round 3
// baseline (2447.765 us; speedup 1.0000x reference)
//
#include <hip/hip_runtime.h>
#include <cstdint>
#include <cstddef>

typedef __bf16 bf16;
typedef __bf16 bf16x8 __attribute__((ext_vector_type(8)));
typedef __bf16 bf16x4 __attribute__((ext_vector_type(4)));
typedef float f32x4 __attribute__((ext_vector_type(4)));

#define S_ 2048
#define H_ 2048
#define MROWS 4096   // B*S

__device__ __forceinline__ void gld_lds16(void* lds, const void* g) {
  __builtin_amdgcn_global_load_lds(
      (const __attribute__((address_space(1))) void*)g,
      (__attribute__((address_space(3))) void*)lds, 16, 0, 0);
}

__device__ __forceinline__ float binf(float w, float kk, float aa) {
  return aa * fminf(fmaxf(kk * w, -1.f), 1.f);
}

// ------------------------------------------------ weight prep (plain bf16)
__global__ __launch_bounds__(256) void prep_w_plain(
    const float* __restrict__ W, bf16* __restrict__ Out, int n,
    const float* __restrict__ kkp, const float* __restrict__ aap)
{
  const float kk = *kkp, aa = *aap;
  int i = (blockIdx.x * 256 + threadIdx.x) * 4;
  if (i >= n) return;
  float4 v = *(const float4*)(W + i);
  bf16x4 o;
  o[0] = (bf16)binf(v.x, kk, aa);
  o[1] = (bf16)binf(v.y, kk, aa);
  o[2] = (bf16)binf(v.z, kk, aa);
  o[3] = (bf16)binf(v.w, kk, aa);
  *(bf16x4*)(Out + i) = o;
}

// ------------------------------------------------ weight prep (hi/lo split)
__global__ __launch_bounds__(256) void prep_w_split(
    const float* __restrict__ W, bf16* __restrict__ Hi, bf16* __restrict__ Lo,
    int n, const float* __restrict__ kkp, const float* __restrict__ aap)
{
  const float kk = *kkp, aa = *aap;
  int i = (blockIdx.x * 256 + threadIdx.x) * 4;
  if (i >= n) return;
  float4 v = *(const float4*)(W + i);
  float w[4] = {binf(v.x, kk, aa), binf(v.y, kk, aa),
                binf(v.z, kk, aa), binf(v.w, kk, aa)};
  bf16x4 h, l;
  #pragma unroll
  for (int j = 0; j < 4; ++j) {
    h[j] = (bf16)w[j];
    l[j] = (bf16)(w[j] - (float)h[j]);
  }
  *(bf16x4*)(Hi + i) = h;
  *(bf16x4*)(Lo + i) = l;
}

// gate/up interleaved at 16-row granularity for one FF chunk of 2816 features.
// G,U are pre-offset to the chunk base. Out rows r in [0,5632):
// t=r>>4 even -> gate feature (t>>1)*16+(r&15); odd -> up.
__global__ __launch_bounds__(256) void prep_w_gu(
    const float* __restrict__ G, const float* __restrict__ U,
    bf16* __restrict__ Out, int n,
    const float* __restrict__ kkp, const float* __restrict__ aap)
{
  const float kk = *kkp, aa = *aap;
  int i = (blockIdx.x * 256 + threadIdx.x) * 4;
  if (i >= n) return;
  int r = i >> 11;          // 2048 cols per row
  int c = i & 2047;
  int t = r >> 4, e = r & 15;
  const float* src = (t & 1) ? U : G;
  int srow = ((t >> 1) << 4) + e;       // 0..2815 within chunk
  float4 v = *(const float4*)(src + (size_t)srow * 2048 + c);
  bf16x4 o;
  o[0] = (bf16)binf(v.x, kk, aa);
  o[1] = (bf16)binf(v.y, kk, aa);
  o[2] = (bf16)binf(v.z, kk, aa);
  o[3] = (bf16)binf(v.w, kk, aa);
  *(bf16x4*)(Out + i) = o;
}

// down_w chunk: W pre-offset to column base; src row stride 5632, out 2816.
__global__ __launch_bounds__(256) void prep_w_down(
    const float* __restrict__ W, bf16* __restrict__ Out,
    const float* __restrict__ kkp, const float* __restrict__ aap)
{
  const float kk = *kkp, aa = *aap;
  const int r = blockIdx.x;             // 0..2047
  for (int c = threadIdx.x * 4; c < 2816; c += 1024) {
    float4 v = *(const float4*)(W + (size_t)r * 5632 + c);
    bf16x4 o;
    o[0] = (bf16)binf(v.x, kk, aa);
    o[1] = (bf16)binf(v.y, kk, aa);
    o[2] = (bf16)binf(v.z, kk, aa);
    o[3] = (bf16)binf(v.w, kk, aa);
    *(bf16x4*)(Out + (size_t)r * 2816 + c) = o;
  }
}

// ------------------------------------------------ rmsnorm
// SPLIT: write hi/lo bf16 pair (for f32-accurate MFMA). else single bf16.
template <bool SPLIT>
__global__ __launch_bounds__(256) void rmsnorm_kernel(
    const float* __restrict__ X, const float* __restrict__ W,
    bf16* __restrict__ O1, bf16* __restrict__ O2)
{
  __shared__ float red[4];
  const int r = blockIdx.x, t = threadIdx.x;
  const float* x = X + (size_t)r * H_;
  float4 a = *(const float4*)(x + t * 8);
  float4 b = *(const float4*)(x + t * 8 + 4);
  float ss = a.x*a.x + a.y*a.y + a.z*a.z + a.w*a.w
           + b.x*b.x + b.y*b.y + b.z*b.z + b.w*b.w;
  #pragma unroll
  for (int o = 32; o > 0; o >>= 1) ss += __shfl_xor(ss, o);
  if ((t & 63) == 0) red[t >> 6] = ss;
  __syncthreads();
  float tot = red[0] + red[1] + red[2] + red[3];
  float rs = rsqrtf(tot * (1.f / (float)H_) + 1e-5f);
  float4 wa = *(const float4*)(W + t * 8);
  float4 wb = *(const float4*)(W + t * 8 + 4);
  float h[8] = {a.x*rs*wa.x, a.y*rs*wa.y, a.z*rs*wa.z, a.w*rs*wa.w,
                b.x*rs*wb.x, b.y*rs*wb.y, b.z*rs*wb.z, b.w*rs*wb.w};
  if constexpr (SPLIT) {
    bf16x8 hi, lo;
    #pragma unroll
    for (int j = 0; j < 8; ++j) {
      hi[j] = (bf16)h[j];
      lo[j] = (bf16)(h[j] - (float)hi[j]);
    }
    *(bf16x8*)(O1 + (size_t)r * H_ + t * 8) = hi;
    *(bf16x8*)(O2 + (size_t)r * H_ + t * 8) = lo;
  } else {
    bf16x8 o8;
    #pragma unroll
    for (int j = 0; j < 8; ++j) o8[j] = (bf16)h[j];
    *(bf16x8*)(O1 + (size_t)r * H_ + t * 8) = o8;
  }
}

// ------------------------------------------------ QKV split-GEMM + fused RoPE
// C[4096,3072] = (Ah+Al)[4096,2048] x (Bh+Bl)[3072,2048]^T via 3 MFMAs
// (hi*hi + hi*lo + lo*hi), f32-accurate. Epilogue applies RoPE in f32 and
// scatters to Qf/Kf/Vf [heads][S][64] f32. One wave covers one 64-col head
// block; rope pair (d,d+32) = acc blocks (j,j+2), same lane.
__global__ __launch_bounds__(256) void gemm_qkv_rope(
    const bf16* __restrict__ Ah, const bf16* __restrict__ Al,
    const bf16* __restrict__ Bh, const bf16* __restrict__ Bl,
    const int* __restrict__ pos,
    float* __restrict__ Qf, float* __restrict__ Kf, float* __restrict__ Vf)
{
  __shared__ alignas(16) bf16 lAh[128 * 64];
  __shared__ alignas(16) bf16 lAl[128 * 64];
  __shared__ alignas(16) bf16 lBh[128 * 64];
  __shared__ alignas(16) bf16 lBl[128 * 64];

  const int tid = threadIdx.x;
  const int lane = tid & 63;
  const int wave = tid >> 6;
  const int wm = wave >> 1;
  const int wn = wave & 1;
  const int l15 = lane & 15;
  const int quad = lane >> 4;

  const size_t row0 = (size_t)blockIdx.y * 128;
  const size_t col0 = (size_t)blockIdx.x * 128;

  size_t offA[4], offB[4];
  int dsto[4];
  #pragma unroll
  for (int i = 0; i < 4; ++i) {
    int s = (wave * 4 + i) * 64 + lane;
    int r = s >> 3;
    int pc = s & 7;
    int lc = pc ^ (r & 7);
    offA[i] = (row0 + r) * 2048 + lc * 8;
    offB[i] = (col0 + r) * 2048 + lc * 8;
    dsto[i] = (wave * 4 + i) * 512;
  }

  int arow[4], brow[4];
  #pragma unroll
  for (int i = 0; i < 4; ++i) {
    arow[i] = wm * 64 + i * 16 + l15;
    brow[i] = wn * 64 + i * 16 + l15;
  }

  f32x4 acc[4][4];
  #pragma unroll
  for (int i = 0; i < 4; ++i)
    #pragma unroll
    for (int j = 0; j < 4; ++j)
      acc[i][j] = f32x4{0.f, 0.f, 0.f, 0.f};

  for (int ks = 0; ks < 32; ++ks) {
    #pragma unroll
    for (int i = 0; i < 4; ++i) {
      gld_lds16(&lAh[dsto[i]], Ah + offA[i]);
      gld_lds16(&lAl[dsto[i]], Al + offA[i]);
      gld_lds16(&lBh[dsto[i]], Bh + offB[i]);
      gld_lds16(&lBl[dsto[i]], Bl + offB[i]);
      offA[i] += 64;
      offB[i] += 64;
    }
    __syncthreads();
    #pragma unroll
    for (int kk = 0; kk < 2; ++kk) {
      bf16x8 ah[4], al[4], bh[4], bl[4];
      #pragma unroll
      for (int i = 0; i < 4; ++i) {
        int pa = ((kk * 4 + quad) ^ (arow[i] & 7)) * 8;
        int pb = ((kk * 4 + quad) ^ (brow[i] & 7)) * 8;
        ah[i] = *(const bf16x8*)&lAh[arow[i] * 64 + pa];
        al[i] = *(const bf16x8*)&lAl[arow[i] * 64 + pa];
        bh[i] = *(const bf16x8*)&lBh[brow[i] * 64 + pb];
        bl[i] = *(const bf16x8*)&lBl[brow[i] * 64 + pb];
      }
      #pragma unroll
      for (int i = 0; i < 4; ++i)
        #pragma unroll
        for (int j = 0; j < 4; ++j) {
          acc[i][j] = __builtin_amdgcn_mfma_f32_16x16x32_bf16(ah[i], bh[j], acc[i][j], 0, 0, 0);
          acc[i][j] = __builtin_amdgcn_mfma_f32_16x16x32_bf16(ah[i], bl[j], acc[i][j], 0, 0, 0);
          acc[i][j] = __builtin_amdgcn_mfma_f32_16x16x32_bf16(al[i], bh[j], acc[i][j], 0, 0, 0);
        }
    }
    __syncthreads();
  }

  // epilogue: C row=quad*4+g, col=l15. Wave head block:
  const int hh = blockIdx.x * 2 + wn;   // 0..47: q(0..31) k(32..39) v(40..47)
  #pragma unroll
  for (int i = 0; i < 4; ++i) {
    #pragma unroll
    for (int g = 0; g < 4; ++g) {
      int r = (int)row0 + wm * 64 + i * 16 + quad * 4 + g;
      int b = r >> 11, s = r & 2047;
      if (hh < 40) {
        float p = (float)pos[r];
        float* dst = (hh < 32)
            ? Qf + ((size_t)(b * 32 + hh) * S_ + s) * 64
            : Kf + ((size_t)(b * 8 + (hh - 32)) * S_ + s) * 64;
        #pragma unroll
        for (int j = 0; j < 2; ++j) {
          int d1 = j * 16 + l15;        // 0..31
          float ang = p * exp2f((float)d1 * -0.41524101186098287f);
          float cs = cosf(ang), sn = sinf(ang);
          float a1 = acc[i][j][g], a2 = acc[i][j + 2][g];
          dst[d1]      = a1 * cs - a2 * sn;
          dst[d1 + 32] = a2 * cs + a1 * sn;
        }
      } else {
        float* dst = Vf + ((size_t)(b * 8 + (hh - 40)) * S_ + s) * 64;
        #pragma unroll
        for (int j = 0; j < 4; ++j)
          dst[j * 16 + l15] = acc[i][j][g];
      }
    }
  }
}

// ------------------------------------------------ GEMM (NT), bf16 MFMA
// MODE 1: f32 out = acc + Res (Res may alias Cout). MODE 2: silu(gate)*up
// from interleaved cols, bf16 out of width N/2.
template <int MODE>
__global__ __launch_bounds__(256) void gemm_bt(
    const bf16* __restrict__ A, const bf16* __restrict__ Bw,
    void* Cout, const float* Res, int N, int K)
{
  __shared__ alignas(16) bf16 ldsA[128 * 64];
  __shared__ alignas(16) bf16 ldsB[128 * 64];

  const int tid = threadIdx.x;
  const int lane = tid & 63;
  const int wave = tid >> 6;
  const int wm = wave >> 1;
  const int wn = wave & 1;
  const int l15 = lane & 15;
  const int quad = lane >> 4;

  const size_t row0 = (size_t)blockIdx.y * 128;
  const size_t col0 = (size_t)blockIdx.x * 128;

  const bf16* aptr[4];
  const bf16* bptr[4];
  bf16* dstA[4];
  bf16* dstB[4];
  #pragma unroll
  for (int i = 0; i < 4; ++i) {
    int s = (wave * 4 + i) * 64 + lane;
    int r = s >> 3;
    int pc = s & 7;
    int lc = pc ^ (r & 7);
    aptr[i] = A + (row0 + r) * (size_t)K + lc * 8;
    bptr[i] = Bw + (col0 + r) * (size_t)K + lc * 8;
    dstA[i] = &ldsA[(wave * 4 + i) * 512];
    dstB[i] = &ldsB[(wave * 4 + i) * 512];
  }

  int arow[4], brow[4];
  #pragma unroll
  for (int i = 0; i < 4; ++i) {
    arow[i] = wm * 64 + i * 16 + l15;
    brow[i] = wn * 64 + i * 16 + l15;
  }

  f32x4 acc[4][4];
  #pragma unroll
  for (int i = 0; i < 4; ++i)
    #pragma unroll
    for (int j = 0; j < 4; ++j)
      acc[i][j] = f32x4{0.f, 0.f, 0.f, 0.f};

  const int ksteps = K >> 6;
  for (int ks = 0; ks < ksteps; ++ks) {
    #pragma unroll
    for (int i = 0; i < 4; ++i) {
      gld_lds16(dstA[i], aptr[i]);
      gld_lds16(dstB[i], bptr[i]);
      aptr[i] += 64;
      bptr[i] += 64;
    }
    __syncthreads();
    #pragma unroll
    for (int kk = 0; kk < 2; ++kk) {
      bf16x8 af[4], bfr[4];
      #pragma unroll
      for (int i = 0; i < 4; ++i) {
        int pa = ((kk * 4 + quad) ^ (arow[i] & 7)) * 8;
        af[i] = *(const bf16x8*)&ldsA[arow[i] * 64 + pa];
        int pb = ((kk * 4 + quad) ^ (brow[i] & 7)) * 8;
        bfr[i] = *(const bf16x8*)&ldsB[brow[i] * 64 + pb];
      }
      #pragma unroll
      for (int i = 0; i < 4; ++i)
        #pragma unroll
        for (int j = 0; j < 4; ++j)
          acc[i][j] = __builtin_amdgcn_mfma_f32_16x16x32_bf16(
              af[i], bfr[j], acc[i][j], 0, 0, 0);
    }
    __syncthreads();
  }

  if constexpr (MODE == 1) {
    float* C = (float*)Cout;
    #pragma unroll
    for (int i = 0; i < 4; ++i) {
      size_t rbase = row0 + wm * 64 + i * 16 + quad * 4;
      #pragma unroll
      for (int j = 0; j < 4; ++j) {
        size_t c = col0 + wn * 64 + j * 16 + l15;
        #pragma unroll
        for (int g = 0; g < 4; ++g) {
          size_t idx = (rbase + g) * (size_t)N + c;
          C[idx] = acc[i][j][g] + Res[idx];
        }
      }
    }
  } else {  // MODE 2
    bf16* C = (bf16*)Cout;
    const int NO = N >> 1;
    #pragma unroll
    for (int i = 0; i < 4; ++i) {
      size_t rbase = row0 + wm * 64 + i * 16 + quad * 4;
      #pragma unroll
      for (int nj = 0; nj < 2; ++nj) {
        size_t f = (size_t)blockIdx.x * 64 + wn * 32 + nj * 16 + l15;
        #pragma unroll
        for (int g = 0; g < 4; ++g) {
          float gv = acc[i][2 * nj][g];
          float uv = acc[i][2 * nj + 1][g];
          float hv = gv / (1.f + __expf(-gv)) * uv;
          C[(rbase + g) * (size_t)NO + f] = (bf16)hv;
        }
      }
    }
  }
}

// ------------------------------------------------ flash attn (f32 QKV)
__global__ __launch_bounds__(128) void flash_attn(
    const float* __restrict__ Q, const float* __restrict__ Kb,
    const float* __restrict__ Vb, bf16* __restrict__ O)
{
  __shared__ alignas(16) float sK[64][68];
  __shared__ alignas(16) float sV[64][68];
  const int t = threadIdx.x;
  const int bh = blockIdx.y;            // b*32+h
  const int b = bh >> 5;
  const int h = bh & 31;
  const int kvh = h >> 2;               // GROUPS=4
  const int q0 = blockIdx.x * 128;
  const int qrow = q0 + t;

  float q[64], o[64];
  {
    const float* qptr = Q + ((size_t)bh * S_ + qrow) * 64;
    #pragma unroll
    for (int c = 0; c < 16; ++c) {
      float4 v = *(const float4*)(qptr + c * 4);
      q[c * 4 + 0] = v.x * 0.125f;
      q[c * 4 + 1] = v.y * 0.125f;
      q[c * 4 + 2] = v.z * 0.125f;
      q[c * 4 + 3] = v.w * 0.125f;
    }
  }
  #pragma unroll
  for (int d = 0; d < 64; ++d) o[d] = 0.f;
  float m = -3.0e38f, l = 0.f;

  const float* kbase = Kb + (size_t)(b * 8 + kvh) * S_ * 64;
  const float* vbase = Vb + (size_t)(b * 8 + kvh) * S_ * 64;

  const int ntiles = (q0 + 128) >> 6;
  for (int kt = 0; kt < ntiles; ++kt) {
    const int kv0 = kt << 6;
    {
      const int rr = t & 63;
      const float* src = ((t >> 6) == 0 ? kbase : vbase) + (size_t)(kv0 + rr) * 64;
      float* dst = (t >> 6) == 0 ? &sK[rr][0] : &sV[rr][0];
      #pragma unroll
      for (int c = 0; c < 16; ++c)
        *(float4*)(dst + c * 4) = *(const float4*)(src + c * 4);
    }
    __syncthreads();
    int jmax = qrow - kv0 + 1;
    if (jmax > 64) jmax = 64;
    for (int j = 0; j < jmax; ++j) {
      const float4* kr = (const float4*)&sK[j][0];
      float s0 = 0.f, s1 = 0.f, s2 = 0.f, s3 = 0.f;
      #pragma unroll
      for (int c = 0; c < 16; ++c) {
        float4 kv = kr[c];
        s0 += q[c * 4 + 0] * kv.x;
        s1 += q[c * 4 + 1] * kv.y;
        s2 += q[c * 4 + 2] * kv.z;
        s3 += q[c * 4 + 3] * kv.w;
      }
      float s = (s0 + s1) + (s2 + s3);
      if (s > m) {
        float corr = __expf(m - s);
        m = s;
        l *= corr;
        #pragma unroll
        for (int d = 0; d < 64; ++d) o[d] *= corr;
      }
      float p = __expf(s - m);
      l += p;
      const float4* vr = (const float4*)&sV[j][0];
      #pragma unroll
      for (int c = 0; c < 16; ++c) {
        float4 vv = vr[c];
        o[c * 4 + 0] += p * vv.x;
        o[c * 4 + 1] += p * vv.y;
        o[c * 4 + 2] += p * vv.z;
        o[c * 4 + 3] += p * vv.w;
      }
    }
    __syncthreads();
  }
  const float inv = 1.f / l;
  bf16* optr = O + (size_t)(b * S_ + qrow) * H_ + h * 64;
  #pragma unroll
  for (int c = 0; c < 8; ++c) {
    bf16x8 v8;
    #pragma unroll
    for (int j = 0; j < 8; ++j) v8[j] = (bf16)(o[c * 8 + j] * inv);
    *(bf16x8*)(optr + c * 8) = v8;
  }
}

// ------------------------------------------------ workspace layout (bytes)
// Peak 109,051,904 B. Overlays rely on strict stream ordering.
static constexpr size_t OFF_WH   = 0;            // 3072x2048 bf16 = 12,582,912
static constexpr size_t OFF_WL   = 12582912;     // 12,582,912
static constexpr size_t OFF_H1HI = 25165824;     // 4096x2048 bf16 = 16,777,216
static constexpr size_t OFF_H1LO = 41943040;
static constexpr size_t OFF_QF   = 58720256;     // 64x2048x64 f32 = 33,554,432
static constexpr size_t OFF_KF   = 92274688;     // 16x2048x64 f32 = 8,388,608
static constexpr size_t OFF_VF   = 100663296;    // end 109,051,904
static constexpr size_t OFF_ATTN = 0;            // over dead WH/WL (16.8 MB)
static constexpr size_t OFF_WO   = 16777216;     // over dead H1HI (8.4 MB)
static constexpr size_t OFF_HID  = 62914560;     // over dead QF (33.6 MB)
static constexpr size_t OFF_H1B  = 0;            // over dead ATTN (16.8 MB)
static constexpr size_t OFF_WGU  = 16777216;     // 5632x2048 bf16 = 23,068,672
static constexpr size_t OFF_H3   = 39845888;     // 4096x2816 bf16, end 62,914,560
static constexpr size_t OFF_WD   = 16777216;     // 2048x2816 bf16 over dead WGU

extern "C" void kernel_launch(void* const* d_in, const int* in_sizes, int n_in,
                              void* d_out, int out_size, void* d_ws, size_t ws_size,
                              hipStream_t stream)
{
  const float* hidden = (const float*)d_in[0];
  // d_in[1] attention_mask: exactly causal -> handled by loop bounds
  const int* pos      = (const int*)d_in[2];
  const float* q_w    = (const float*)d_in[3];
  const float* k_w    = (const float*)d_in[4];
  const float* v_w    = (const float*)d_in[5];
  const float* o_w    = (const float*)d_in[6];
  const float* gate_w = (const float*)d_in[7];
  const float* up_w   = (const float*)d_in[8];
  const float* down_w = (const float*)d_in[9];
  const float* ln1    = (const float*)d_in[10];
  const float* ln2    = (const float*)d_in[11];
  const float* kkp    = (const float*)d_in[12];
  const float* aap    = (const float*)d_in[13];
  float* out = (float*)d_out;

  char* ws = (char*)d_ws;
  bf16* WH   = (bf16*)(ws + OFF_WH);
  bf16* WL   = (bf16*)(ws + OFF_WL);
  bf16* H1HI = (bf16*)(ws + OFF_H1HI);
  bf16* H1LO = (bf16*)(ws + OFF_H1LO);
  float* QF  = (float*)(ws + OFF_QF);
  float* KF  = (float*)(ws + OFF_KF);
  float* VF  = (float*)(ws + OFF_VF);
  bf16* ATTN = (bf16*)(ws + OFF_ATTN);
  bf16* WO   = (bf16*)(ws + OFF_WO);
  float* HID = (float*)(ws + OFF_HID);
  bf16* H1B  = (bf16*)(ws + OFF_H1B);
  bf16* WGU  = (bf16*)(ws + OFF_WGU);
  bf16* H3   = (bf16*)(ws + OFF_H3);
  bf16* WD   = (bf16*)(ws + OFF_WD);

  // --- attention block (f32-accurate scores) ---
  prep_w_split<<<4096, 256, 0, stream>>>(q_w, WH, WL, 2048 * 2048, kkp, aap);
  prep_w_split<<<1024, 256, 0, stream>>>(k_w, WH + (size_t)2048 * 2048,
                                         WL + (size_t)2048 * 2048, 512 * 2048, kkp, aap);
  prep_w_split<<<1024, 256, 0, stream>>>(v_w, WH + (size_t)2560 * 2048,
                                         WL + (size_t)2560 * 2048, 512 * 2048, kkp, aap);
  rmsnorm_kernel<true><<<MROWS, 256, 0, stream>>>(hidden, ln1, H1HI, H1LO);
  gemm_qkv_rope<<<dim3(24, 32), 256, 0, stream>>>(H1HI, H1LO, WH, WL, pos, QF, KF, VF);
  flash_attn<<<dim3(16, 64), 128, 0, stream>>>(QF, KF, VF, ATTN);
  prep_w_plain<<<4096, 256, 0, stream>>>(o_w, WO, 2048 * 2048, kkp, aap);
  gemm_bt<1><<<dim3(16, 32), 256, 0, stream>>>(ATTN, WO, HID, hidden, 2048, 2048);

  // --- MLP block, FF chunked 2x2816 (split-K accumulate into out) ---
  rmsnorm_kernel<false><<<MROWS, 256, 0, stream>>>(HID, ln2, H1B, nullptr);
  for (int c = 0; c < 2; ++c) {
    const float* resp = (c == 0) ? HID : out;
    prep_w_gu<<<11264, 256, 0, stream>>>(gate_w + (size_t)c * 2816 * 2048,
                                         up_w + (size_t)c * 2816 * 2048,
                                         WGU, 5632 * 2048, kkp, aap);
    gemm_bt<2><<<dim3(44, 32), 256, 0, stream>>>(H1B, WGU, H3, nullptr, 5632, 2048);
    prep_w_down<<<2048, 256, 0, stream>>>(down_w + (size_t)c * 2816, WD, kkp, aap);
    gemm_bt<1><<<dim3(16, 32), 256, 0, stream>>>(H3, WD, out, resp, 2048, 2816);
  }

  (void)in_sizes; (void)n_in; (void)out_size; (void)ws_size;
}

// Round 4
// 1299.473 us; speedup vs baseline: 1.8837x; 1.8837x over previous
//
#include <hip/hip_runtime.h>
#include <cstdint>
#include <cstddef>

typedef __bf16 bf16;
typedef __bf16 bf16x8 __attribute__((ext_vector_type(8)));
typedef __bf16 bf16x4 __attribute__((ext_vector_type(4)));
typedef float f32x4 __attribute__((ext_vector_type(4)));

#define S_ 2048
#define H_ 2048
#define MROWS 4096   // B*S

__device__ __forceinline__ void gld_lds16(void* lds, const void* g) {
  __builtin_amdgcn_global_load_lds(
      (const __attribute__((address_space(1))) void*)g,
      (__attribute__((address_space(3))) void*)lds, 16, 0, 0);
}

__device__ __forceinline__ float binf(float w, float kk, float aa) {
  return aa * fminf(fmaxf(kk * w, -1.f), 1.f);
}

// ------------------------------------------------ weight prep (plain bf16)
__global__ __launch_bounds__(256) void prep_w_plain(
    const float* __restrict__ W, bf16* __restrict__ Out, int n,
    const float* __restrict__ kkp, const float* __restrict__ aap)
{
  const float kk = *kkp, aa = *aap;
  int i = (blockIdx.x * 256 + threadIdx.x) * 4;
  if (i >= n) return;
  float4 v = *(const float4*)(W + i);
  bf16x4 o;
  o[0] = (bf16)binf(v.x, kk, aa);
  o[1] = (bf16)binf(v.y, kk, aa);
  o[2] = (bf16)binf(v.z, kk, aa);
  o[3] = (bf16)binf(v.w, kk, aa);
  *(bf16x4*)(Out + i) = o;
}

// ------------------------------------------------ weight prep (hi/lo split)
__global__ __launch_bounds__(256) void prep_w_split(
    const float* __restrict__ W, bf16* __restrict__ Hi, bf16* __restrict__ Lo,
    int n, const float* __restrict__ kkp, const float* __restrict__ aap)
{
  const float kk = *kkp, aa = *aap;
  int i = (blockIdx.x * 256 + threadIdx.x) * 4;
  if (i >= n) return;
  float4 v = *(const float4*)(W + i);
  float w[4] = {binf(v.x, kk, aa), binf(v.y, kk, aa),
                binf(v.z, kk, aa), binf(v.w, kk, aa)};
  bf16x4 h, l;
  #pragma unroll
  for (int j = 0; j < 4; ++j) {
    h[j] = (bf16)w[j];
    l[j] = (bf16)(w[j] - (float)h[j]);
  }
  *(bf16x4*)(Hi + i) = h;
  *(bf16x4*)(Lo + i) = l;
}

// gate/up interleaved at 16-row granularity for one FF chunk of 2816 features.
__global__ __launch_bounds__(256) void prep_w_gu(
    const float* __restrict__ G, const float* __restrict__ U,
    bf16* __restrict__ Out, int n,
    const float* __restrict__ kkp, const float* __restrict__ aap)
{
  const float kk = *kkp, aa = *aap;
  int i = (blockIdx.x * 256 + threadIdx.x) * 4;
  if (i >= n) return;
  int r = i >> 11;          // 2048 cols per row
  int c = i & 2047;
  int t = r >> 4, e = r & 15;
  const float* src = (t & 1) ? U : G;
  int srow = ((t >> 1) << 4) + e;       // 0..2815 within chunk
  float4 v = *(const float4*)(src + (size_t)srow * 2048 + c);
  bf16x4 o;
  o[0] = (bf16)binf(v.x, kk, aa);
  o[1] = (bf16)binf(v.y, kk, aa);
  o[2] = (bf16)binf(v.z, kk, aa);
  o[3] = (bf16)binf(v.w, kk, aa);
  *(bf16x4*)(Out + i) = o;
}

// down_w chunk: W pre-offset to column base; src row stride 5632, out 2816.
__global__ __launch_bounds__(256) void prep_w_down(
    const float* __restrict__ W, bf16* __restrict__ Out,
    const float* __restrict__ kkp, const float* __restrict__ aap)
{
  const float kk = *kkp, aa = *aap;
  const int r = blockIdx.x;             // 0..2047
  for (int c = threadIdx.x * 4; c < 2816; c += 1024) {
    float4 v = *(const float4*)(W + (size_t)r * 5632 + c);
    bf16x4 o;
    o[0] = (bf16)binf(v.x, kk, aa);
    o[1] = (bf16)binf(v.y, kk, aa);
    o[2] = (bf16)binf(v.z, kk, aa);
    o[3] = (bf16)binf(v.w, kk, aa);
    *(bf16x4*)(Out + (size_t)r * 2816 + c) = o;
  }
}

// ------------------------------------------------ rmsnorm
template <bool SPLIT>
__global__ __launch_bounds__(256) void rmsnorm_kernel(
    const float* __restrict__ X, const float* __restrict__ W,
    bf16* __restrict__ O1, bf16* __restrict__ O2)
{
  __shared__ float red[4];
  const int r = blockIdx.x, t = threadIdx.x;
  const float* x = X + (size_t)r * H_;
  float4 a = *(const float4*)(x + t * 8);
  float4 b = *(const float4*)(x + t * 8 + 4);
  float ss = a.x*a.x + a.y*a.y + a.z*a.z + a.w*a.w
           + b.x*b.x + b.y*b.y + b.z*b.z + b.w*b.w;
  #pragma unroll
  for (int o = 32; o > 0; o >>= 1) ss += __shfl_xor(ss, o);
  if ((t & 63) == 0) red[t >> 6] = ss;
  __syncthreads();
  float tot = red[0] + red[1] + red[2] + red[3];
  float rs = rsqrtf(tot * (1.f / (float)H_) + 1e-5f);
  float4 wa = *(const float4*)(W + t * 8);
  float4 wb = *(const float4*)(W + t * 8 + 4);
  float h[8] = {a.x*rs*wa.x, a.y*rs*wa.y, a.z*rs*wa.z, a.w*rs*wa.w,
                b.x*rs*wb.x, b.y*rs*wb.y, b.z*rs*wb.z, b.w*rs*wb.w};
  if constexpr (SPLIT) {
    bf16x8 hi, lo;
    #pragma unroll
    for (int j = 0; j < 8; ++j) {
      hi[j] = (bf16)h[j];
      lo[j] = (bf16)(h[j] - (float)hi[j]);
    }
    *(bf16x8*)(O1 + (size_t)r * H_ + t * 8) = hi;
    *(bf16x8*)(O2 + (size_t)r * H_ + t * 8) = lo;
  } else {
    bf16x8 o8;
    #pragma unroll
    for (int j = 0; j < 8; ++j) o8[j] = (bf16)h[j];
    *(bf16x8*)(O1 + (size_t)r * H_ + t * 8) = o8;
  }
}

// ------------------------------------------------ QKV split-GEMM + fused RoPE
// C[4096,3072] = (Ah+Al) x (Bh+Bl)^T via 3 MFMAs, f32-accurate. Epilogue
// applies RoPE in f32 and emits Q/K as bf16 hi/lo pairs + V bf16,
// laid out [head][S][64] for the MFMA flash kernel.
__global__ __launch_bounds__(256) void gemm_qkv_rope(
    const bf16* __restrict__ Ah, const bf16* __restrict__ Al,
    const bf16* __restrict__ Bh, const bf16* __restrict__ Bl,
    const int* __restrict__ pos,
    bf16* __restrict__ QHI, bf16* __restrict__ QLO,
    bf16* __restrict__ KHI, bf16* __restrict__ KLO,
    bf16* __restrict__ VB)
{
  __shared__ alignas(16) bf16 lAh[128 * 64];
  __shared__ alignas(16) bf16 lAl[128 * 64];
  __shared__ alignas(16) bf16 lBh[128 * 64];
  __shared__ alignas(16) bf16 lBl[128 * 64];

  const int tid = threadIdx.x;
  const int lane = tid & 63;
  const int wave = tid >> 6;
  const int wm = wave >> 1;
  const int wn = wave & 1;
  const int l15 = lane & 15;
  const int quad = lane >> 4;

  const size_t row0 = (size_t)blockIdx.y * 128;
  const size_t col0 = (size_t)blockIdx.x * 128;

  size_t offA[4], offB[4];
  int dsto[4];
  #pragma unroll
  for (int i = 0; i < 4; ++i) {
    int s = (wave * 4 + i) * 64 + lane;
    int r = s >> 3;
    int pc = s & 7;
    int lc = pc ^ (r & 7);
    offA[i] = (row0 + r) * 2048 + lc * 8;
    offB[i] = (col0 + r) * 2048 + lc * 8;
    dsto[i] = (wave * 4 + i) * 512;
  }

  int arow[4], brow[4];
  #pragma unroll
  for (int i = 0; i < 4; ++i) {
    arow[i] = wm * 64 + i * 16 + l15;
    brow[i] = wn * 64 + i * 16 + l15;
  }

  f32x4 acc[4][4];
  #pragma unroll
  for (int i = 0; i < 4; ++i)
    #pragma unroll
    for (int j = 0; j < 4; ++j)
      acc[i][j] = f32x4{0.f, 0.f, 0.f, 0.f};

  for (int ks = 0; ks < 32; ++ks) {
    #pragma unroll
    for (int i = 0; i < 4; ++i) {
      gld_lds16(&lAh[dsto[i]], Ah + offA[i]);
      gld_lds16(&lAl[dsto[i]], Al + offA[i]);
      gld_lds16(&lBh[dsto[i]], Bh + offB[i]);
      gld_lds16(&lBl[dsto[i]], Bl + offB[i]);
      offA[i] += 64;
      offB[i] += 64;
    }
    __syncthreads();
    #pragma unroll
    for (int kk = 0; kk < 2; ++kk) {
      bf16x8 ah[4], al[4], bh[4], bl[4];
      #pragma unroll
      for (int i = 0; i < 4; ++i) {
        int pa = ((kk * 4 + quad) ^ (arow[i] & 7)) * 8;
        int pb = ((kk * 4 + quad) ^ (brow[i] & 7)) * 8;
        ah[i] = *(const bf16x8*)&lAh[arow[i] * 64 + pa];
        al[i] = *(const bf16x8*)&lAl[arow[i] * 64 + pa];
        bh[i] = *(const bf16x8*)&lBh[brow[i] * 64 + pb];
        bl[i] = *(const bf16x8*)&lBl[brow[i] * 64 + pb];
      }
      #pragma unroll
      for (int i = 0; i < 4; ++i)
        #pragma unroll
        for (int j = 0; j < 4; ++j) {
          acc[i][j] = __builtin_amdgcn_mfma_f32_16x16x32_bf16(ah[i], bh[j], acc[i][j], 0, 0, 0);
          acc[i][j] = __builtin_amdgcn_mfma_f32_16x16x32_bf16(ah[i], bl[j], acc[i][j], 0, 0, 0);
          acc[i][j] = __builtin_amdgcn_mfma_f32_16x16x32_bf16(al[i], bh[j], acc[i][j], 0, 0, 0);
        }
    }
    __syncthreads();
  }

  // epilogue: C row=quad*4+g, col=l15. hh: 0..31 q, 32..39 k, 40..47 v
  const int hh = blockIdx.x * 2 + wn;
  #pragma unroll
  for (int i = 0; i < 4; ++i) {
    #pragma unroll
    for (int g = 0; g < 4; ++g) {
      int r = (int)row0 + wm * 64 + i * 16 + quad * 4 + g;
      int b = r >> 11, s = r & 2047;
      if (hh < 40) {
        float p = (float)pos[r];
        bf16* dhi;
        bf16* dlo;
        size_t base;
        if (hh < 32) {
          base = ((size_t)(b * 32 + hh) * S_ + s) * 64;
          dhi = QHI; dlo = QLO;
        } else {
          base = ((size_t)(b * 8 + (hh - 32)) * S_ + s) * 64;
          dhi = KHI; dlo = KLO;
        }
        #pragma unroll
        for (int j = 0; j < 2; ++j) {
          int d1 = j * 16 + l15;        // 0..31
          float ang = p * exp2f((float)d1 * -0.41524101186098287f);
          float cs = cosf(ang), sn = sinf(ang);
          float a1 = acc[i][j][g], a2 = acc[i][j + 2][g];
          float v1 = a1 * cs - a2 * sn;
          float v2 = a2 * cs + a1 * sn;
          bf16 h1 = (bf16)v1, h2 = (bf16)v2;
          dhi[base + d1]      = h1;
          dlo[base + d1]      = (bf16)(v1 - (float)h1);
          dhi[base + d1 + 32] = h2;
          dlo[base + d1 + 32] = (bf16)(v2 - (float)h2);
        }
      } else {
        size_t base = ((size_t)(b * 8 + (hh - 40)) * S_ + s) * 64;
        #pragma unroll
        for (int j = 0; j < 4; ++j)
          VB[base + j * 16 + l15] = (bf16)acc[i][j][g];
      }
    }
  }
}

// ------------------------------------------------ GEMM (NT), bf16 MFMA
template <int MODE>
__global__ __launch_bounds__(256) void gemm_bt(
    const bf16* __restrict__ A, const bf16* __restrict__ Bw,
    void* Cout, const float* Res, int N, int K)
{
  __shared__ alignas(16) bf16 ldsA[128 * 64];
  __shared__ alignas(16) bf16 ldsB[128 * 64];

  const int tid = threadIdx.x;
  const int lane = tid & 63;
  const int wave = tid >> 6;
  const int wm = wave >> 1;
  const int wn = wave & 1;
  const int l15 = lane & 15;
  const int quad = lane >> 4;

  const size_t row0 = (size_t)blockIdx.y * 128;
  const size_t col0 = (size_t)blockIdx.x * 128;

  const bf16* aptr[4];
  const bf16* bptr[4];
  bf16* dstA[4];
  bf16* dstB[4];
  #pragma unroll
  for (int i = 0; i < 4; ++i) {
    int s = (wave * 4 + i) * 64 + lane;
    int r = s >> 3;
    int pc = s & 7;
    int lc = pc ^ (r & 7);
    aptr[i] = A + (row0 + r) * (size_t)K + lc * 8;
    bptr[i] = Bw + (col0 + r) * (size_t)K + lc * 8;
    dstA[i] = &ldsA[(wave * 4 + i) * 512];
    dstB[i] = &ldsB[(wave * 4 + i) * 512];
  }

  int arow[4], brow[4];
  #pragma unroll
  for (int i = 0; i < 4; ++i) {
    arow[i] = wm * 64 + i * 16 + l15;
    brow[i] = wn * 64 + i * 16 + l15;
  }

  f32x4 acc[4][4];
  #pragma unroll
  for (int i = 0; i < 4; ++i)
    #pragma unroll
    for (int j = 0; j < 4; ++j)
      acc[i][j] = f32x4{0.f, 0.f, 0.f, 0.f};

  const int ksteps = K >> 6;
  for (int ks = 0; ks < ksteps; ++ks) {
    #pragma unroll
    for (int i = 0; i < 4; ++i) {
      gld_lds16(dstA[i], aptr[i]);
      gld_lds16(dstB[i], bptr[i]);
      aptr[i] += 64;
      bptr[i] += 64;
    }
    __syncthreads();
    #pragma unroll
    for (int kk = 0; kk < 2; ++kk) {
      bf16x8 af[4], bfr[4];
      #pragma unroll
      for (int i = 0; i < 4; ++i) {
        int pa = ((kk * 4 + quad) ^ (arow[i] & 7)) * 8;
        af[i] = *(const bf16x8*)&ldsA[arow[i] * 64 + pa];
        int pb = ((kk * 4 + quad) ^ (brow[i] & 7)) * 8;
        bfr[i] = *(const bf16x8*)&ldsB[brow[i] * 64 + pb];
      }
      #pragma unroll
      for (int i = 0; i < 4; ++i)
        #pragma unroll
        for (int j = 0; j < 4; ++j)
          acc[i][j] = __builtin_amdgcn_mfma_f32_16x16x32_bf16(
              af[i], bfr[j], acc[i][j], 0, 0, 0);
    }
    __syncthreads();
  }

  if constexpr (MODE == 1) {
    float* C = (float*)Cout;
    #pragma unroll
    for (int i = 0; i < 4; ++i) {
      size_t rbase = row0 + wm * 64 + i * 16 + quad * 4;
      #pragma unroll
      for (int j = 0; j < 4; ++j) {
        size_t c = col0 + wn * 64 + j * 16 + l15;
        #pragma unroll
        for (int g = 0; g < 4; ++g) {
          size_t idx = (rbase + g) * (size_t)N + c;
          C[idx] = acc[i][j][g] + Res[idx];
        }
      }
    }
  } else {  // MODE 2: gate/up interleaved -> silu(g)*u, bf16 out width N/2
    bf16* C = (bf16*)Cout;
    const int NO = N >> 1;
    #pragma unroll
    for (int i = 0; i < 4; ++i) {
      size_t rbase = row0 + wm * 64 + i * 16 + quad * 4;
      #pragma unroll
      for (int nj = 0; nj < 2; ++nj) {
        size_t f = (size_t)blockIdx.x * 64 + wn * 32 + nj * 16 + l15;
        #pragma unroll
        for (int g = 0; g < 4; ++g) {
          float gv = acc[i][2 * nj][g];
          float uv = acc[i][2 * nj + 1][g];
          float hv = gv / (1.f + __expf(-gv)) * uv;
          C[(rbase + g) * (size_t)NO + f] = (bf16)hv;
        }
      }
    }
  }
}

// ------------------------------------------------ MFMA flash attention
// Block 256 = 4 waves; q-tile 128 rows (wave w owns rows [w*32,w*32+32)).
// S = Q K^T with hi/lo split (3 MFMAs) -> f32-accurate scores; online
// softmax in C-layout (row=quad*4+g, col=l15); P -> LDS (xor-swizzled)
// -> A-frags; P*V with V^T staged in LDS. Causal via loop bound + mask.
__global__ __launch_bounds__(256) void flash_attn_mfma(
    const bf16* __restrict__ QHI, const bf16* __restrict__ QLO,
    const bf16* __restrict__ KHI, const bf16* __restrict__ KLO,
    const bf16* __restrict__ VB, bf16* __restrict__ O)
{
  __shared__ alignas(16) bf16 sKh[64 * 64];
  __shared__ alignas(16) bf16 sKl[64 * 64];
  __shared__ alignas(16) bf16 sVt[64 * 64];   // [dim][key], swizzled
  __shared__ alignas(16) bf16 sP[128 * 64];   // [q][key], swizzled

  const int tid = threadIdx.x;
  const int lane = tid & 63;
  const int w = tid >> 6;
  const int l15 = lane & 15;
  const int quad = lane >> 4;

  const int qblk = 15 - blockIdx.x;     // longest blocks dispatched first
  const int bh = blockIdx.y;            // b*32+h
  const int b = bh >> 5;
  const int h = bh & 31;
  const int kvh = h >> 2;
  const int q0 = qblk * 128;
  const int wrow0 = q0 + w * 32;        // this wave's first q row

  // Q fragments (A-layout): rows wrow0 + mb*16 + l15, k = ks*32 + quad*8
  bf16x8 qh[2][2], ql[2][2];
  {
    const size_t qbase = (size_t)bh * S_ * 64;
    #pragma unroll
    for (int mb = 0; mb < 2; ++mb)
      #pragma unroll
      for (int ks = 0; ks < 2; ++ks) {
        size_t off = qbase + (size_t)(wrow0 + mb * 16 + l15) * 64 + ks * 32 + quad * 8;
        qh[mb][ks] = *(const bf16x8*)(QHI + off);
        ql[mb][ks] = *(const bf16x8*)(QLO + off);
      }
  }

  f32x4 accO[2][4];
  float m_r[2][4], l_r[2][4];
  #pragma unroll
  for (int mb = 0; mb < 2; ++mb) {
    #pragma unroll
    for (int nd = 0; nd < 4; ++nd) accO[mb][nd] = f32x4{0.f, 0.f, 0.f, 0.f};
    #pragma unroll
    for (int g = 0; g < 4; ++g) { m_r[mb][g] = -3.0e38f; l_r[mb][g] = 0.f; }
  }

  const size_t kbase = (size_t)(b * 8 + kvh) * S_ * 64;
  const int ntiles = (q0 + 128) >> 6;

  for (int kt = 0; kt < ntiles; ++kt) {
    const int kv0 = kt << 6;
    // ---- stage K hi/lo (b128, xor-swizzled) ----
    #pragma unroll
    for (int i = 0; i < 2; ++i) {
      int slot = i * 256 + tid;
      int key = slot >> 3, ch = slot & 7;
      int chs = ch ^ (key & 7);
      size_t gofs = kbase + (size_t)(kv0 + key) * 64 + ch * 8;
      *(bf16x8*)&sKh[key * 64 + chs * 8] = *(const bf16x8*)(KHI + gofs);
      *(bf16x8*)&sKl[key * 64 + chs * 8] = *(const bf16x8*)(KLO + gofs);
    }
    // ---- stage V transposed: sVt[dim][key] ----
    #pragma unroll
    for (int i = 0; i < 2; ++i) {
      int key = lane;
      int dg = i * 4 + w;
      bf16x8 v = *(const bf16x8*)(VB + kbase + (size_t)(kv0 + key) * 64 + dg * 8);
      #pragma unroll
      for (int j = 0; j < 8; ++j) {
        int dim = dg * 8 + j;
        int chs = (key >> 3) ^ (dim & 7);
        sVt[dim * 64 + chs * 8 + (key & 7)] = v[j];
      }
    }
    __syncthreads();

    if (kv0 <= wrow0 + 31) {
      // ---- S = Q K^T (3-way split) ----
      f32x4 s[2][4];
      #pragma unroll
      for (int mb = 0; mb < 2; ++mb)
        #pragma unroll
        for (int nb = 0; nb < 4; ++nb)
          s[mb][nb] = f32x4{0.f, 0.f, 0.f, 0.f};
      #pragma unroll
      for (int ks = 0; ks < 2; ++ks) {
        bf16x8 kh[4], kl[4];
        #pragma unroll
        for (int nb = 0; nb < 4; ++nb) {
          int key = nb * 16 + l15;
          int chs = (ks * 4 + quad) ^ (key & 7);
          kh[nb] = *(const bf16x8*)&sKh[key * 64 + chs * 8];
          kl[nb] = *(const bf16x8*)&sKl[key * 64 + chs * 8];
        }
        #pragma unroll
        for (int mb = 0; mb < 2; ++mb)
          #pragma unroll
          for (int nb = 0; nb < 4; ++nb) {
            s[mb][nb] = __builtin_amdgcn_mfma_f32_16x16x32_bf16(qh[mb][ks], kh[nb], s[mb][nb], 0, 0, 0);
            s[mb][nb] = __builtin_amdgcn_mfma_f32_16x16x32_bf16(qh[mb][ks], kl[nb], s[mb][nb], 0, 0, 0);
            s[mb][nb] = __builtin_amdgcn_mfma_f32_16x16x32_bf16(ql[mb][ks], kh[nb], s[mb][nb], 0, 0, 0);
          }
      }
      // ---- scale + causal mask ----
      const bool diag = (kv0 + 63 > wrow0);
      #pragma unroll
      for (int mb = 0; mb < 2; ++mb)
        #pragma unroll
        for (int nb = 0; nb < 4; ++nb)
          #pragma unroll
          for (int g = 0; g < 4; ++g) {
            float sv = s[mb][nb][g] * 0.125f;
            if (diag) {
              int key = kv0 + nb * 16 + l15;
              int qr = wrow0 + mb * 16 + quad * 4 + g;
              if (key > qr) sv = -1.0e30f;
            }
            s[mb][nb][g] = sv;
          }
      // ---- online softmax ----
      #pragma unroll
      for (int mb = 0; mb < 2; ++mb)
        #pragma unroll
        for (int g = 0; g < 4; ++g) {
          float mx = fmaxf(fmaxf(s[mb][0][g], s[mb][1][g]),
                           fmaxf(s[mb][2][g], s[mb][3][g]));
          #pragma unroll
          for (int xm = 1; xm <= 8; xm <<= 1)
            mx = fmaxf(mx, __shfl_xor(mx, xm));
          float mnew = fmaxf(m_r[mb][g], mx);
          float corr = __expf(m_r[mb][g] - mnew);
          m_r[mb][g] = mnew;
          l_r[mb][g] *= corr;
          #pragma unroll
          for (int nd = 0; nd < 4; ++nd) accO[mb][nd][g] *= corr;
        }
      // ---- p = exp(s-m); partial l; pack to sP ----
      #pragma unroll
      for (int mb = 0; mb < 2; ++mb)
        #pragma unroll
        for (int nb = 0; nb < 4; ++nb)
          #pragma unroll
          for (int g = 0; g < 4; ++g) {
            float p = __expf(s[mb][nb][g] - m_r[mb][g]);
            l_r[mb][g] += p;
            int q = w * 32 + mb * 16 + quad * 4 + g;
            int key = nb * 16 + l15;
            int chs = (key >> 3) ^ (q & 7);
            sP[q * 64 + chs * 8 + (key & 7)] = (bf16)p;
          }
      // ---- O += P * V (same-wave LDS round trip, no barrier needed) ----
      #pragma unroll
      for (int ks = 0; ks < 2; ++ks) {
        bf16x8 pa[2], vf[4];
        #pragma unroll
        for (int mb = 0; mb < 2; ++mb) {
          int q = w * 32 + mb * 16 + l15;
          int chs = (ks * 4 + quad) ^ (q & 7);
          pa[mb] = *(const bf16x8*)&sP[q * 64 + chs * 8];
        }
        #pragma unroll
        for (int nd = 0; nd < 4; ++nd) {
          int dim = nd * 16 + l15;
          int chs = (ks * 4 + quad) ^ (dim & 7);
          vf[nd] = *(const bf16x8*)&sVt[dim * 64 + chs * 8];
        }
        #pragma unroll
        for (int mb = 0; mb < 2; ++mb)
          #pragma unroll
          for (int nd = 0; nd < 4; ++nd)
            accO[mb][nd] = __builtin_amdgcn_mfma_f32_16x16x32_bf16(
                pa[mb], vf[nd], accO[mb][nd], 0, 0, 0);
      }
    }
    __syncthreads();
  }

  // ---- finalize: l reduce across l15, scale, store ----
  float inv[2][4];
  #pragma unroll
  for (int mb = 0; mb < 2; ++mb)
    #pragma unroll
    for (int g = 0; g < 4; ++g) {
      float lt = l_r[mb][g];
      #pragma unroll
      for (int xm = 1; xm <= 8; xm <<= 1) lt += __shfl_xor(lt, xm);
      inv[mb][g] = 1.f / lt;
    }
  #pragma unroll
  for (int mb = 0; mb < 2; ++mb)
    #pragma unroll
    for (int g = 0; g < 4; ++g) {
      int srow = wrow0 + mb * 16 + quad * 4 + g;
      bf16* optr = O + ((size_t)b * S_ + srow) * H_ + h * 64;
      #pragma unroll
      for (int nd = 0; nd < 4; ++nd)
        optr[nd * 16 + l15] = (bf16)(accO[mb][nd][g] * inv[mb][g]);
    }
}

// ------------------------------------------------ workspace layout (bytes)
static constexpr size_t OFF_WH   = 0;            // 12,582,912
static constexpr size_t OFF_WL   = 12582912;     // 12,582,912
static constexpr size_t OFF_H1HI = 25165824;     // 16,777,216
static constexpr size_t OFF_H1LO = 41943040;     // 16,777,216
static constexpr size_t OFF_QHI  = 58720256;     // 16,777,216
static constexpr size_t OFF_QLO  = 75497472;     // 16,777,216
static constexpr size_t OFF_KHI  = 92274688;     //  4,194,304
static constexpr size_t OFF_KLO  = 96468992;     //  4,194,304
static constexpr size_t OFF_VB   = 100663296;    //  4,194,304 -> end 104,857,600
static constexpr size_t OFF_ATTN = 0;            // over dead WH/WL
static constexpr size_t OFF_WO   = 25165824;     // over dead H1HI
static constexpr size_t OFF_HID  = 58720256;     // over dead QHI/QLO (f32, 33.5MB)
static constexpr size_t OFF_H1B  = 92274688;     // over dead KHI/KLO
static constexpr size_t OFF_WGU  = 0;            // over dead ATTN (23.1MB)
static constexpr size_t OFF_H3   = 25165824;     // 23.1MB, ends 48,234,496
static constexpr size_t OFF_WD   = 0;            // over dead WGU (11.5MB)

extern "C" void kernel_launch(void* const* d_in, const int* in_sizes, int n_in,
                              void* d_out, int out_size, void* d_ws, size_t ws_size,
                              hipStream_t stream)
{
  const float* hidden = (const float*)d_in[0];
  // d_in[1] attention_mask: exactly causal -> handled by loop bounds
  const int* pos      = (const int*)d_in[2];
  const float* q_w    = (const float*)d_in[3];
  const float* k_w    = (const float*)d_in[4];
  const float* v_w    = (const float*)d_in[5];
  const float* o_w    = (const float*)d_in[6];
  const float* gate_w = (const float*)d_in[7];
  const float* up_w   = (const float*)d_in[8];
  const float* down_w = (const float*)d_in[9];
  const float* ln1    = (const float*)d_in[10];
  const float* ln2    = (const float*)d_in[11];
  const float* kkp    = (const float*)d_in[12];
  const float* aap    = (const float*)d_in[13];
  float* out = (float*)d_out;

  char* ws = (char*)d_ws;
  bf16* WH   = (bf16*)(ws + OFF_WH);
  bf16* WL   = (bf16*)(ws + OFF_WL);
  bf16* H1HI = (bf16*)(ws + OFF_H1HI);
  bf16* H1LO = (bf16*)(ws + OFF_H1LO);
  bf16* QHI  = (bf16*)(ws + OFF_QHI);
  bf16* QLO  = (bf16*)(ws + OFF_QLO);
  bf16* KHI  = (bf16*)(ws + OFF_KHI);
  bf16* KLO  = (bf16*)(ws + OFF_KLO);
  bf16* VB   = (bf16*)(ws + OFF_VB);
  bf16* ATTN = (bf16*)(ws + OFF_ATTN);
  bf16* WO   = (bf16*)(ws + OFF_WO);
  float* HID = (float*)(ws + OFF_HID);
  bf16* H1B  = (bf16*)(ws + OFF_H1B);
  bf16* WGU  = (bf16*)(ws + OFF_WGU);
  bf16* H3   = (bf16*)(ws + OFF_H3);
  bf16* WD   = (bf16*)(ws + OFF_WD);

  // --- attention block (f32-accurate scores) ---
  prep_w_split<<<4096, 256, 0, stream>>>(q_w, WH, WL, 2048 * 2048, kkp, aap);
  prep_w_split<<<1024, 256, 0, stream>>>(k_w, WH + (size_t)2048 * 2048,
                                         WL + (size_t)2048 * 2048, 512 * 2048, kkp, aap);
  prep_w_split<<<1024, 256, 0, stream>>>(v_w, WH + (size_t)2560 * 2048,
                                         WL + (size_t)2560 * 2048, 512 * 2048, kkp, aap);
  rmsnorm_kernel<true><<<MROWS, 256, 0, stream>>>(hidden, ln1, H1HI, H1LO);
  gemm_qkv_rope<<<dim3(24, 32), 256, 0, stream>>>(H1HI, H1LO, WH, WL, pos,
                                                  QHI, QLO, KHI, KLO, VB);
  flash_attn_mfma<<<dim3(16, 64), 256, 0, stream>>>(QHI, QLO, KHI, KLO, VB, ATTN);
  prep_w_plain<<<4096, 256, 0, stream>>>(o_w, WO, 2048 * 2048, kkp, aap);
  gemm_bt<1><<<dim3(16, 32), 256, 0, stream>>>(ATTN, WO, HID, hidden, 2048, 2048);

  // --- MLP block, FF chunked 2x2816 (split-K accumulate into out) ---
  rmsnorm_kernel<false><<<MROWS, 256, 0, stream>>>(HID, ln2, H1B, nullptr);
  for (int c = 0; c < 2; ++c) {
    const float* resp = (c == 0) ? HID : out;
    prep_w_gu<<<11264, 256, 0, stream>>>(gate_w + (size_t)c * 2816 * 2048,
                                         up_w + (size_t)c * 2816 * 2048,
                                         WGU, 5632 * 2048, kkp, aap);
    gemm_bt<2><<<dim3(44, 32), 256, 0, stream>>>(H1B, WGU, H3, nullptr, 5632, 2048);
    prep_w_down<<<2048, 256, 0, stream>>>(down_w + (size_t)c * 2816, WD, kkp, aap);
    gemm_bt<1><<<dim3(16, 32), 256, 0, stream>>>(H3, WD, out, resp, 2048, 2816);
  }

  (void)in_sizes; (void)n_in; (void)out_size; (void)ws_size;
}